// Round 1
// baseline (590.318 us; speedup 1.0000x reference)
//
#include <hip/hip_runtime.h>
#include <math.h>

// ---------------------------------------------------------------------------
// v2 pipeline: sample-derived threshold replaces the full-data 4096-bin LDS
// histogram (which was same-address DS-atomic bound, ~4x over read roofline).
//
//   memset    : zero counters + sample hist (16.4 KB)
//   k_sample  : 4096-bin hist of a 262144-element sample (1 MB read)
//   k_thresh  : T = bin lower edge whose sample suffix-count >= C0 (~4x margin
//               over rank-from-top r). True count above T ~ 27-80K; margins
//               are Poisson-astronomical both sides (vs. incumbent's CAP=256).
//   k_pass1   : ONE BW-bound pass over x: wave/block max -> atomicMax,
//               exact count |x|>T (per-lane adds, no atomics), candidate
//               append (~30/block, LDS-staged). Zero per-element atomics.
//   k_quant   : pure streaming quantize (scale = 127/max).
//   k_select  : EXACT 3-level radix select (bits 10/11/10) over candidates;
//               8x-replicated pass-A LDS hist (bank-spread), parallel
//               shfl-prefix bin-find (no serial thread0 scans).
//
// Exactness: candidates = all elements strictly > T. They are exactly the
// top-m of the descending sort (m = count_above). Answer (rank r from top,
// r = n-1-k) is the (m-1-r)-th smallest candidate when m > r (guaranteed by
// threshold margin on this data).
// ---------------------------------------------------------------------------

// Workspace layout (uint32 words):
#define WS_MAXBITS 0          // atomicMax of |x| bits          (memset 0)
#define WS_NABOVE  1          // exact count of |x| > T         (memset 0)
#define WS_CANDCNT 2          // candidates stored              (memset 0)
#define WS_TBITS   3          // threshold bits (k_thresh)      (memset 0)
#define WS_SHIST   8          // 4096-word sample histogram     (memset 0)
#define SHIST_WORDS 4096
#define WS_CAND    4104       // candidate value buffer
#define CANDMAX    262144     // 1 MB of candidates (expect ~31K)
#define NBLK       1024
#define CAP        512        // per-block candidate staging (expect ~30)

typedef float floatx4 __attribute__((ext_vector_type(4)));

// ---------------------------------------------------------------------------
extern "C" __global__ void __launch_bounds__(256)
k_sample(const float* __restrict__ x, long n, unsigned int* __restrict__ ws) {
    __shared__ unsigned int lh[SHIST_WORDS];
    for (int i = threadIdx.x; i < SHIST_WORDS; i += 256) lh[i] = 0;
    __syncthreads();
    // 256 blocks x 256 threads x 4 floats = 262144 samples; each block reads
    // one contiguous (coalesced) 4 KB chunk, chunks spread evenly over x.
    long seg = (n / 256) & ~3L;
    long idx = (long)blockIdx.x * seg + (long)threadIdx.x * 4;
    if (seg >= 4 && idx + 4 <= n) {
        float4 v = *(const float4*)(x + idx);
        unsigned int a0 = __float_as_uint(v.x) & 0x7fffffffu;
        unsigned int a1 = __float_as_uint(v.y) & 0x7fffffffu;
        unsigned int a2 = __float_as_uint(v.z) & 0x7fffffffu;
        unsigned int a3 = __float_as_uint(v.w) & 0x7fffffffu;
        atomicAdd(&lh[a0 >> 20], 1u);
        atomicAdd(&lh[a1 >> 20], 1u);
        atomicAdd(&lh[a2 >> 20], 1u);
        atomicAdd(&lh[a3 >> 20], 1u);
    }
    __syncthreads();
    unsigned int rot = (blockIdx.x * 1297u) & (SHIST_WORDS - 1);
    for (int i = threadIdx.x; i < SHIST_WORDS; i += 256) {
        unsigned int bin = (i + rot) & (SHIST_WORDS - 1);
        unsigned int c = lh[bin];
        if (c) atomicAdd(&ws[WS_SHIST + bin], c);
    }
}

// ---------------------------------------------------------------------------
extern "C" __global__ void __launch_bounds__(256)
k_thresh(unsigned int* __restrict__ ws, unsigned int C0) {
    // T = lower edge of the highest bin b such that (#samples in bins >= b)
    // >= C0. Parallel: each thread owns 16 bins; suffix sums over chunks.
    __shared__ unsigned int csum[256];
    int tid = threadIdx.x;
    const unsigned int* sh = ws + WS_SHIST;
    unsigned int s = 0;
    for (int i = 0; i < 16; i++) s += sh[tid * 16 + i];
    csum[tid] = s;
    __syncthreads();
    unsigned int suf = 0;
    for (int u = tid; u < 256; u++) suf += csum[u];   // independent loads, pipelined
    unsigned int sufnext = suf - s;
    if (suf >= C0 && sufnext < C0) {
        // crossing bin is in my chunk; scan it from the top
        unsigned int acc = sufnext;
        for (int i = 15; i >= 0; i--) {
            acc += sh[tid * 16 + i];
            if (acc >= C0) { ws[WS_TBITS] = ((unsigned int)(tid * 16 + i)) << 20; break; }
        }
    }
    if (tid == 0 && suf < C0) ws[WS_TBITS] = 0u;  // degenerate tiny-n guard
}

// ---------------------------------------------------------------------------
extern "C" __global__ void __launch_bounds__(256)
k_pass1(const float* __restrict__ x, long n, unsigned int* __restrict__ ws) {
    __shared__ unsigned int lbuf[CAP];
    __shared__ unsigned int lcnt;
    __shared__ unsigned int wred[4], wcnt[4], sbase[1];
    if (threadIdx.x == 0) lcnt = 0;
    __syncthreads();
    unsigned int T = ws[WS_TBITS];

    long n4 = n >> 2;
    const float4* x4 = (const float4*)x;
    unsigned int mymax = 0, myc = 0;
    long stride = (long)gridDim.x * 256;
    long i = (long)blockIdx.x * 256 + threadIdx.x;
    for (; i + stride < n4; i += 2 * stride) {
        float4 v0 = x4[i];
        float4 v1 = x4[i + stride];
        unsigned int a0 = __float_as_uint(v0.x) & 0x7fffffffu;
        unsigned int a1 = __float_as_uint(v0.y) & 0x7fffffffu;
        unsigned int a2 = __float_as_uint(v0.z) & 0x7fffffffu;
        unsigned int a3 = __float_as_uint(v0.w) & 0x7fffffffu;
        unsigned int b0 = __float_as_uint(v1.x) & 0x7fffffffu;
        unsigned int b1 = __float_as_uint(v1.y) & 0x7fffffffu;
        unsigned int b2 = __float_as_uint(v1.z) & 0x7fffffffu;
        unsigned int b3 = __float_as_uint(v1.w) & 0x7fffffffu;
        mymax = max(mymax, max(max(a0, a1), max(a2, a3)));
        mymax = max(mymax, max(max(b0, b1), max(b2, b3)));
        myc += (a0 > T) + (a1 > T) + (a2 > T) + (a3 > T);
        myc += (b0 > T) + (b1 > T) + (b2 > T) + (b3 > T);
        if (a0 > T) { unsigned int p = atomicAdd(&lcnt, 1u); if (p < CAP) lbuf[p] = a0; }
        if (a1 > T) { unsigned int p = atomicAdd(&lcnt, 1u); if (p < CAP) lbuf[p] = a1; }
        if (a2 > T) { unsigned int p = atomicAdd(&lcnt, 1u); if (p < CAP) lbuf[p] = a2; }
        if (a3 > T) { unsigned int p = atomicAdd(&lcnt, 1u); if (p < CAP) lbuf[p] = a3; }
        if (b0 > T) { unsigned int p = atomicAdd(&lcnt, 1u); if (p < CAP) lbuf[p] = b0; }
        if (b1 > T) { unsigned int p = atomicAdd(&lcnt, 1u); if (p < CAP) lbuf[p] = b1; }
        if (b2 > T) { unsigned int p = atomicAdd(&lcnt, 1u); if (p < CAP) lbuf[p] = b2; }
        if (b3 > T) { unsigned int p = atomicAdd(&lcnt, 1u); if (p < CAP) lbuf[p] = b3; }
    }
    for (; i < n4; i += stride) {
        float4 v = x4[i];
        unsigned int a0 = __float_as_uint(v.x) & 0x7fffffffu;
        unsigned int a1 = __float_as_uint(v.y) & 0x7fffffffu;
        unsigned int a2 = __float_as_uint(v.z) & 0x7fffffffu;
        unsigned int a3 = __float_as_uint(v.w) & 0x7fffffffu;
        mymax = max(mymax, max(max(a0, a1), max(a2, a3)));
        myc += (a0 > T) + (a1 > T) + (a2 > T) + (a3 > T);
        if (a0 > T) { unsigned int p = atomicAdd(&lcnt, 1u); if (p < CAP) lbuf[p] = a0; }
        if (a1 > T) { unsigned int p = atomicAdd(&lcnt, 1u); if (p < CAP) lbuf[p] = a1; }
        if (a2 > T) { unsigned int p = atomicAdd(&lcnt, 1u); if (p < CAP) lbuf[p] = a2; }
        if (a3 > T) { unsigned int p = atomicAdd(&lcnt, 1u); if (p < CAP) lbuf[p] = a3; }
    }
    if (blockIdx.x == 0 && threadIdx.x < (int)(n & 3)) {
        unsigned int a = __float_as_uint(x[n4 * 4 + threadIdx.x]) & 0x7fffffffu;
        mymax = max(mymax, a);
        myc += (a > T);
        if (a > T) { unsigned int p = atomicAdd(&lcnt, 1u); if (p < CAP) lbuf[p] = a; }
    }

    for (int off = 32; off > 0; off >>= 1) {
        mymax = max(mymax, __shfl_down(mymax, off, 64));
        myc += __shfl_down(myc, off, 64);
    }
    int lane = threadIdx.x & 63, wid = threadIdx.x >> 6;
    if (lane == 0) { wred[wid] = mymax; wcnt[wid] = myc; }
    __syncthreads();   // also orders all lbuf/lcnt atomics
    if (threadIdx.x == 0) {
        unsigned int bm = max(max(wred[0], wred[1]), max(wred[2], wred[3]));
        unsigned int bc = wcnt[0] + wcnt[1] + wcnt[2] + wcnt[3];
        atomicMax(&ws[WS_MAXBITS], bm);
        atomicAdd(&ws[WS_NABOVE], bc);
        unsigned int c = lcnt; if (c > CAP) c = CAP;
        wred[0] = c;
        sbase[0] = atomicAdd(&ws[WS_CANDCNT], c);
    }
    __syncthreads();
    unsigned int c = wred[0], base = sbase[0];
    for (unsigned int e = threadIdx.x; e < c; e += 256)
        if (base + e < CANDMAX) ws[WS_CAND + base + e] = lbuf[e];
}

// ---------------------------------------------------------------------------
extern "C" __global__ void __launch_bounds__(256)
k_quant(const float* __restrict__ x, float* __restrict__ out, long n,
        unsigned int* __restrict__ ws) {
    float xmax = __uint_as_float(ws[WS_MAXBITS]);
    float scale = 127.0f / xmax;
    float inv = 1.0f / scale;

    long n4 = n >> 2;
    const float4* x4 = (const float4*)x;
    floatx4* out4 = (floatx4*)out;
    long stride = (long)gridDim.x * 256;
    long i = (long)blockIdx.x * 256 + threadIdx.x;
    for (; i + stride < n4; i += 2 * stride) {
        float4 v0 = x4[i];
        float4 v1 = x4[i + stride];
        floatx4 r0, r1;
        r0.x = fminf(fmaxf(rintf(v0.x * scale), -127.0f), 127.0f) * inv;
        r0.y = fminf(fmaxf(rintf(v0.y * scale), -127.0f), 127.0f) * inv;
        r0.z = fminf(fmaxf(rintf(v0.z * scale), -127.0f), 127.0f) * inv;
        r0.w = fminf(fmaxf(rintf(v0.w * scale), -127.0f), 127.0f) * inv;
        r1.x = fminf(fmaxf(rintf(v1.x * scale), -127.0f), 127.0f) * inv;
        r1.y = fminf(fmaxf(rintf(v1.y * scale), -127.0f), 127.0f) * inv;
        r1.z = fminf(fmaxf(rintf(v1.z * scale), -127.0f), 127.0f) * inv;
        r1.w = fminf(fmaxf(rintf(v1.w * scale), -127.0f), 127.0f) * inv;
        __builtin_nontemporal_store(r0, &out4[i]);
        __builtin_nontemporal_store(r1, &out4[i + stride]);
    }
    for (; i < n4; i += stride) {
        float4 v = x4[i];
        floatx4 r;
        r.x = fminf(fmaxf(rintf(v.x * scale), -127.0f), 127.0f) * inv;
        r.y = fminf(fmaxf(rintf(v.y * scale), -127.0f), 127.0f) * inv;
        r.z = fminf(fmaxf(rintf(v.z * scale), -127.0f), 127.0f) * inv;
        r.w = fminf(fmaxf(rintf(v.w * scale), -127.0f), 127.0f) * inv;
        __builtin_nontemporal_store(r, &out4[i]);
    }
    if (blockIdx.x == 0 && threadIdx.x < (int)(n & 3)) {
        long t = n4 * 4 + threadIdx.x;
        out[t] = fminf(fmaxf(rintf(x[t] * scale), -127.0f), 127.0f) * inv;
    }
}

// ---------------------------------------------------------------------------
// Block-wide: find smallest bin b with cumulative(bins[0..b]) > j.
// Each thread owns `per` contiguous bins. Parallel shfl prefix, no serial scans.
__device__ __forceinline__ void find_bin(const unsigned int* bins, int per,
                                         unsigned int j, unsigned int* sfind,
                                         unsigned int& out_b, unsigned int& out_jrem) {
    int tid = threadIdx.x, lane = tid & 63, wid = tid >> 6;
    unsigned int s = 0;
    for (int i = 0; i < per; i++) s += bins[tid * per + i];
    unsigned int inc = s;
    for (int off = 1; off < 64; off <<= 1) {
        unsigned int t = __shfl_up(inc, off, 64);
        if (lane >= off) inc += t;
    }
    if (lane == 63) sfind[wid] = inc;
    __syncthreads();
    unsigned int wbase = 0;
    for (int w = 0; w < wid; w++) wbase += sfind[w];
    unsigned int excl = wbase + inc - s;
    if (j >= excl && j < excl + s) {       // exactly one winner
        unsigned int acc = excl;
        for (int i = 0; i < per; i++) {
            unsigned int c = bins[tid * per + i];
            if (acc + c > j) { sfind[4] = (unsigned int)(tid * per + i); sfind[5] = j - acc; break; }
            acc += c;
        }
    }
    __syncthreads();
    out_b = sfind[4];
    out_jrem = sfind[5];
    __syncthreads();   // sfind reused by next call
}

extern "C" __global__ void __launch_bounds__(256)
k_select(unsigned int* __restrict__ ws, float* __restrict__ out_last, long r) {
    __shared__ unsigned int h8[8 * 1025];   // pass A: 1024 bins x 8 copies (bank-spread)
    __shared__ unsigned int hm[1024];
    __shared__ unsigned int h2[2048];
    __shared__ unsigned int h3[1024];
    __shared__ unsigned int sfind[8];
    int tid = threadIdx.x;
    if (tid < 8) sfind[tid] = 0;

    unsigned int m = ws[WS_NABOVE];
    unsigned int mc = ws[WS_CANDCNT]; if (mc > CANDMAX) mc = CANDMAX;
    long jl = (long)m - 1 - r; if (jl < 0) jl = 0;   // j-th smallest candidate
    unsigned int j = (unsigned int)jl;
    const unsigned int* cand = ws + WS_CAND;

    // pass A: top 10 bits (u>>21), 8 replicated copies to spread DS-atomic conflicts
    for (int i = tid; i < 8 * 1025; i += 256) h8[i] = 0;
    __syncthreads();
    unsigned int rep = (unsigned int)(tid & 7) * 1025u;
    for (unsigned int i = tid; i < mc; i += 256)
        atomicAdd(&h8[rep + (cand[i] >> 21)], 1u);
    __syncthreads();
    for (int b = tid; b < 1024; b += 256) {
        unsigned int s = 0;
        for (int c = 0; c < 8; c++) s += h8[c * 1025 + b];
        hm[b] = s;
    }
    __syncthreads();
    unsigned int b1, j2;
    find_bin(hm, 4, j, sfind, b1, j2);

    // pass B: middle 11 bits
    for (int i = tid; i < 2048; i += 256) h2[i] = 0;
    __syncthreads();
    for (unsigned int i = tid; i < mc; i += 256) {
        unsigned int u = cand[i];
        if ((u >> 21) == b1) atomicAdd(&h2[(u >> 10) & 2047u], 1u);
    }
    __syncthreads();
    unsigned int b2, j3;
    find_bin(h2, 8, j2, sfind, b2, j3);

    // pass C: low 10 bits
    unsigned int pref = (b1 << 11) | b2;
    for (int i = tid; i < 1024; i += 256) h3[i] = 0;
    __syncthreads();
    for (unsigned int i = tid; i < mc; i += 256) {
        unsigned int u = cand[i];
        if ((u >> 10) == pref) atomicAdd(&h3[u & 1023u], 1u);
    }
    __syncthreads();
    unsigned int b3, j4;
    find_bin(h3, 4, j3, sfind, b3, j4);
    (void)j4;

    if (tid == 0) {
        unsigned int ans = (b1 << 21) | (b2 << 10) | b3;
        float clampv = __uint_as_float(ans);
        out_last[0] = (float)(100.0 * 0.99 + (double)clampv * 0.01);
    }
}

// ---------------------------------------------------------------------------
extern "C" void kernel_launch(void* const* d_in, const int* in_sizes, int n_in,
                              void* d_out, int out_size, void* d_ws, size_t ws_size,
                              hipStream_t stream) {
    const float* x = (const float*)d_in[0];
    long n = (long)in_sizes[0];
    float* out = (float*)d_out;
    unsigned int* ws = (unsigned int*)d_ws;

    // k = round(0.9999 * n) - 1, same double arithmetic as Python
    long k = (long)llround((99.99 / 100.0) * (double)n) - 1;
    if (k < 0) k = 0;
    if (k >= n) k = n - 1;
    long r = n - 1 - k;   // rank from the top (=6711 for this input)

    // sample-count threshold: ~4x margin over expected sample count at rank r
    unsigned int C0 = (unsigned int)(4.0 * (double)(r + 1) * 262144.0 / (double)n) + 1u;
    if (C0 < 64u) C0 = 64u;

    // zero counters + threshold + sample histogram (16.4 KB)
    (void)hipMemsetAsync(d_ws, 0, (WS_SHIST + SHIST_WORDS) * sizeof(unsigned int),
                         stream);

    k_sample<<<256, 256, 0, stream>>>(x, n, ws);
    k_thresh<<<1, 256, 0, stream>>>(ws, C0);
    k_pass1<<<NBLK, 256, 0, stream>>>(x, n, ws);
    k_quant<<<NBLK, 256, 0, stream>>>(x, out, n, ws);
    k_select<<<1, 256, 0, stream>>>(ws, out + n, r);
}